// Round 4
// baseline (882.329 us; speedup 1.0000x reference)
//
#include <hip/hip_runtime.h>
#include <hip/hip_bf16.h>

// ---------- types ----------
typedef __bf16 bf16x8_t __attribute__((ext_vector_type(8)));
typedef float f32x4_t __attribute__((ext_vector_type(4)));
typedef float f32x16_t __attribute__((ext_vector_type(16)));
typedef int i32x4_t __attribute__((ext_vector_type(4)));
typedef int i32x8_t __attribute__((ext_vector_type(8)));

#define GLDS(gp, lp) __builtin_amdgcn_global_load_lds(                        \
    (const __attribute__((address_space(1))) void*)(gp),                      \
    (__attribute__((address_space(3))) void*)(lp), 16, 0, 0)

// ---------- fast tanh ----------
__device__ __forceinline__ float fast_tanh(float z) {
  float zc = fminf(10.0f, fmaxf(-10.0f, z));
  float e = __expf(2.0f * zc);
  return 1.0f - 2.0f / (e + 1.0f);
}

// pack 4 floats -> 4 fp8 e4m3 bytes (HW cvt => matches MFMA format)
__device__ __forceinline__ int pack_fp8x4(float a, float b, float c, float d) {
  int w = __builtin_amdgcn_cvt_pk_fp8_f32(a, b, 0, false);
  w = __builtin_amdgcn_cvt_pk_fp8_f32(c, d, w, true);
  return w;
}

// ---------- 1) feats (fp8 e4m3): feats[b, d*16+k] = tanh((x-c)*s) ----------
__global__ __launch_bounds__(256) void feats_kernel(
    const float* __restrict__ x, const float* __restrict__ c,
    const float* __restrict__ s, unsigned char* __restrict__ out) {
  int idx = blockIdx.x * 256 + threadIdx.x;  // (b,d) pair; 4096*1024 total
  int d = idx & 1023;
  float xv = x[idx];
  const float4* c4 = (const float4*)(c + d * 16);
  const float4* s4 = (const float4*)(s + d * 16);
  int w[4];
#pragma unroll
  for (int g = 0; g < 4; ++g) {
    float4 cc = c4[g], ss = s4[g];
    float t0 = fast_tanh((xv - cc.x) * ss.x);
    float t1 = fast_tanh((xv - cc.y) * ss.y);
    float t2 = fast_tanh((xv - cc.z) * ss.z);
    float t3 = fast_tanh((xv - cc.w) * ss.w);
    w[g] = pack_fp8x4(t0, t1, t2, t3);
  }
  *(uint4*)(out + (size_t)idx * 16) = make_uint4(w[0], w[1], w[2], w[3]);
}

// ---------- 2) transpose+cast fp32 [R][C] -> fp8 [C][R] scaled by 128 ----------
__global__ __launch_bounds__(256) void transpose_fp8(
    const float* __restrict__ src, unsigned char* __restrict__ dst, int R, int C) {
  __shared__ float tile[64][65];
  const int c0 = blockIdx.x * 64, r0 = blockIdx.y * 64;
  const int t = threadIdx.x;
  const int rr = t >> 4, cc4 = (t & 15) * 4;
#pragma unroll
  for (int p = 0; p < 4; ++p) {
    int row = rr + p * 16;
    float4 v = *(const float4*)(src + (size_t)(r0 + row) * C + c0 + cc4);
    tile[row][cc4 + 0] = v.x;
    tile[row][cc4 + 1] = v.y;
    tile[row][cc4 + 2] = v.z;
    tile[row][cc4 + 3] = v.w;
  }
  __syncthreads();
  const int drow = t >> 2, seg = (t & 3) * 16;
  int w[4];
#pragma unroll
  for (int g = 0; g < 4; ++g) {
    float a = tile[seg + g * 4 + 0][drow] * 128.0f;
    float b = tile[seg + g * 4 + 1][drow] * 128.0f;
    float cc = tile[seg + g * 4 + 2][drow] * 128.0f;
    float d = tile[seg + g * 4 + 3][drow] * 128.0f;
    w[g] = pack_fp8x4(a, b, cc, d);
  }
  *(uint4*)(dst + (size_t)(c0 + drow) * R + r0 + seg) = make_uint4(w[0], w[1], w[2], w[3]);
}

// ---------- 3) transpose+cast fp32 [R][C] -> bf16 [Cpad][R], zero-fill ----------
__global__ __launch_bounds__(256) void transpose_cast(
    const float* __restrict__ src, __hip_bfloat16* __restrict__ dst,
    int R, int C, int Cpad) {
  __shared__ float tile[64][65];
  const int c0 = blockIdx.x * 64, r0 = blockIdx.y * 64;
  const int t = threadIdx.x;
  const int rr = t >> 4, cc4 = (t & 15) * 4;
#pragma unroll
  for (int p = 0; p < 4; ++p) {
    int row = rr + p * 16;
    int cbase = c0 + cc4;
    float4 v;
    if (cbase + 3 < C) {
      v = *(const float4*)(src + (size_t)(r0 + row) * C + cbase);
    } else {
      v.x = (cbase + 0 < C) ? src[(size_t)(r0 + row) * C + cbase + 0] : 0.0f;
      v.y = (cbase + 1 < C) ? src[(size_t)(r0 + row) * C + cbase + 1] : 0.0f;
      v.z = (cbase + 2 < C) ? src[(size_t)(r0 + row) * C + cbase + 2] : 0.0f;
      v.w = (cbase + 3 < C) ? src[(size_t)(r0 + row) * C + cbase + 3] : 0.0f;
    }
    tile[row][cc4 + 0] = v.x;
    tile[row][cc4 + 1] = v.y;
    tile[row][cc4 + 2] = v.z;
    tile[row][cc4 + 3] = v.w;
  }
  __syncthreads();
#pragma unroll
  for (int p = 0; p < 2; ++p) {
    int i = t + 256 * p;
    int drow = i >> 3;
    int seg = (i & 7) * 8;
    int dc = c0 + drow;
    alignas(16) __hip_bfloat16 vals[8];
#pragma unroll
    for (int j = 0; j < 8; ++j) vals[j] = __float2bfloat16(tile[seg + j][drow]);
    if (dc < Cpad)
      *(uint4*)(dst + (size_t)dc * R + r0 + seg) = *(const uint4*)vals;
  }
}

// ---------- 4) GEMM1: MX-fp8 32x32x64, 256x256 tile, BK=64, 3-stage pipeline ----------
// A [M][K] fp8, Bt [N][K] fp8 (pre-scaled x128).
// LDS: 64-B rows, 4x16B slots; row r stores global k-group g at slot g^((r>>1)&3)
// (conflict-free for the 32-row frag reads). 3 buffers, prefetch 2 tiles ahead,
// counted s_waitcnt vmcnt(4) -- never drains to 0 in the main loop (T4).
// out: phi[m*N+n] = bf16(sigmoid(acc/128 + bias[n]))
__global__ __launch_bounds__(512, 2) void gemm1_mx32(
    const unsigned char* __restrict__ A, const unsigned char* __restrict__ Bt,
    const float* __restrict__ bias, __hip_bfloat16* __restrict__ outb,
    int M, int N, int K) {
  __shared__ unsigned char As[3][256 * 64];  // 48 KB
  __shared__ unsigned char Bs[3][256 * 64];  // 48 KB
  const int tid = threadIdx.x;
  const int wave = tid >> 6, lane = tid & 63;
  const int wm = (wave >> 2) * 128, wn = (wave & 3) * 64;  // 2M x 4N waves

  // XCD swizzle (nwg=256, bijective) + 4x8 rectangle per XCD for L2 reuse
  const int bid = blockIdx.x;
  const int swz = (bid & 7) * 32 + (bid >> 3);
  const int gq = swz >> 5, u = swz & 31;
  const int gm0 = ((gq >> 1) * 4 + (u >> 3)) * 256;
  const int gn0 = ((gq & 1) * 8 + (u & 7)) * 256;

  // staging: chunk c = p*512 + tid (16B); row = c>>2; stored slot sg = c&3;
  // global k-group g = sg ^ ((row>>1)&3); lds byte = c*16
  const unsigned char* ga[2];
  const unsigned char* gb[2];
  int ldso[2];
#pragma unroll
  for (int p = 0; p < 2; ++p) {
    int c = p * 512 + tid;
    int row = c >> 2;
    int g = (c & 3) ^ ((row >> 1) & 3);
    ga[p] = A + (size_t)(gm0 + row) * K + g * 16;
    gb[p] = Bt + (size_t)(gn0 + row) * K + g * 16;
    ldso[p] = c * 16;
  }

  f32x16_t acc[4][2] = {};
  const int fr = lane & 31, q = lane >> 5;  // frag row; k-half (32B)

  const int NT = K >> 6;
  // prologue: stage tiles 0 and 1 into buffers 0,1 (4 loads each per thread)
#pragma unroll
  for (int s = 0; s < 2; ++s) {
#pragma unroll
    for (int p = 0; p < 2; ++p) {
      GLDS(ga[p] + s * 64, &As[s][ldso[p]]);
      GLDS(gb[p] + s * 64, &Bs[s][ldso[p]]);
    }
  }

  for (int t = 0; t < NT; ++t) {
    // tile t ready when the 4 oldest loads land; tile t+1's 4 stay in flight
    if (t + 1 < NT) {
      asm volatile("s_waitcnt vmcnt(4)" ::: "memory");
    } else {
      asm volatile("s_waitcnt vmcnt(0)" ::: "memory");
    }
    __builtin_amdgcn_s_barrier();
    __builtin_amdgcn_sched_barrier(0);

    // prefetch tile t+2 into the buffer freed by tile t-1
    if (t + 2 < NT) {
      unsigned char* An = (unsigned char*)As[(t + 2) % 3];
      unsigned char* Bn = (unsigned char*)Bs[(t + 2) % 3];
      const int ko = (t + 2) << 6;
#pragma unroll
      for (int p = 0; p < 2; ++p) {
        GLDS(ga[p] + ko, An + ldso[p]);
        GLDS(gb[p] + ko, Bn + ldso[p]);
      }
    }

    const unsigned char* Ac = As[t % 3];
    const unsigned char* Bc = Bs[t % 3];

    // b-frags: rows wn+j*32+fr, k-half q (two swizzled 16B slots)
    i32x8_t b[2];
#pragma unroll
    for (int j = 0; j < 2; ++j) {
      int rb = wn + j * 32 + fr;
      int f = (rb >> 1) & 3;
      i32x4_t lo = *(const i32x4_t*)(Bc + rb * 64 + (((2 * q) ^ f) * 16));
      i32x4_t hi = *(const i32x4_t*)(Bc + rb * 64 + (((2 * q + 1) ^ f) * 16));
      b[j] = __builtin_shufflevector(lo, hi, 0, 1, 2, 3, 4, 5, 6, 7);
    }
#pragma unroll
    for (int i = 0; i < 4; ++i) {
      int ra = wm + i * 32 + fr;
      int f = (ra >> 1) & 3;
      i32x4_t lo = *(const i32x4_t*)(Ac + ra * 64 + (((2 * q) ^ f) * 16));
      i32x4_t hi = *(const i32x4_t*)(Ac + ra * 64 + (((2 * q + 1) ^ f) * 16));
      i32x8_t a = __builtin_shufflevector(lo, hi, 0, 1, 2, 3, 4, 5, 6, 7);
      __builtin_amdgcn_s_setprio(1);
      acc[i][0] = __builtin_amdgcn_mfma_scale_f32_32x32x64_f8f6f4(
          a, b[0], acc[i][0], 0, 0, 0, 0x7F7F7F7F, 0, 0x7F7F7F7F);
      acc[i][1] = __builtin_amdgcn_mfma_scale_f32_32x32x64_f8f6f4(
          a, b[1], acc[i][1], 0, 0, 0, 0x7F7F7F7F, 0, 0x7F7F7F7F);
      __builtin_amdgcn_s_setprio(0);
    }
  }

  // C/D (32x32): col = lane&31, row = (r&3) + 8*(r>>2) + 4*(lane>>5)
  const int cn = lane & 31, cq = lane >> 5;
#pragma unroll
  for (int j = 0; j < 2; ++j) {
    int n = gn0 + wn + j * 32 + cn;
    float bv = bias[n];
#pragma unroll
    for (int i = 0; i < 4; ++i) {
#pragma unroll
      for (int r = 0; r < 16; ++r) {
        int m = gm0 + wm + i * 32 + (r & 3) + 8 * (r >> 2) + 4 * cq;
        float v = acc[i][j][r] * 0.0078125f + bv;  // /128 de-scale of Wb
        float phi = 1.0f / (1.0f + __expf(-v));
        outb[(size_t)m * N + n] = __float2bfloat16(phi);
      }
    }
  }
}

// ---------- 5) GEMM2 fused: full-K bf16, cross-iter double-buffer, bias+mask ----------
// out[m, n] = phi[m,:] @ Wht[n,:] + bh[n]   for n < 1000; out row stride 1000.
__global__ __launch_bounds__(256) void gemm2_full(
    const __hip_bfloat16* __restrict__ A, const __hip_bfloat16* __restrict__ Bt,
    const float* __restrict__ bh, float* __restrict__ out,
    int M, int N, int K) {
  __shared__ __hip_bfloat16 As[2][2][128 * 32];  // dbuf x k-half, 32 KB
  __shared__ __hip_bfloat16 Bs[2][2][128 * 32];  // 32 KB
  const int tid = threadIdx.x;
  const int wave = tid >> 6, lane = tid & 63;
  const int wm = (wave >> 1) * 64, wn = (wave & 1) * 64;
  const int gm0 = blockIdx.y * 128, gn0 = blockIdx.x * 128;

  const int t1 = tid, t2 = tid + 256;
  const __hip_bfloat16* Ag0 = A + (size_t)(gm0 + (t1 >> 2)) * K + (t1 & 3) * 8;
  const __hip_bfloat16* Ag1 = A + (size_t)(gm0 + (t2 >> 2)) * K + (t2 & 3) * 8;
  const __hip_bfloat16* Bg0 = Bt + (size_t)(gn0 + (t1 >> 2)) * K + (t1 & 3) * 8;
  const __hip_bfloat16* Bg1 = Bt + (size_t)(gn0 + (t2 >> 2)) * K + (t2 & 3) * 8;

  f32x4_t acc[4][4] = {};
  const int fr = lane & 15, fk = (lane >> 4) * 8;

  // prologue: stage k-iter 0 into buf 0
#pragma unroll
  for (int h = 0; h < 2; ++h) {
    GLDS(Ag0 + h * 32, &As[0][h][t1 * 8]);
    GLDS(Ag1 + h * 32, &As[0][h][t2 * 8]);
    GLDS(Bg0 + h * 32, &Bs[0][h][t1 * 8]);
    GLDS(Bg1 + h * 32, &Bs[0][h][t2 * 8]);
  }
  Ag0 += 64; Ag1 += 64; Bg0 += 64; Bg1 += 64;
  __syncthreads();

  const int nk = K >> 6;
  for (int it = 0; it < nk; ++it) {
    const int cur = it & 1;
    if (it + 1 < nk) {
      const int nxt = cur ^ 1;
#pragma unroll
      for (int h = 0; h < 2; ++h) {
        GLDS(Ag0 + h * 32, &As[nxt][h][t1 * 8]);
        GLDS(Ag1 + h * 32, &As[nxt][h][t2 * 8]);
        GLDS(Bg0 + h * 32, &Bs[nxt][h][t1 * 8]);
        GLDS(Bg1 + h * 32, &Bs[nxt][h][t2 * 8]);
      }
      Ag0 += 64; Ag1 += 64; Bg0 += 64; Bg1 += 64;
    }
#pragma unroll
    for (int h = 0; h < 2; ++h) {
      bf16x8_t a[4], b[4];
#pragma unroll
      for (int i = 0; i < 4; ++i) {
        a[i] = *(const bf16x8_t*)(&As[cur][h][(wm + i * 16 + fr) * 32 + fk]);
        b[i] = *(const bf16x8_t*)(&Bs[cur][h][(wn + i * 16 + fr) * 32 + fk]);
      }
#pragma unroll
      for (int i = 0; i < 4; ++i)
#pragma unroll
        for (int j = 0; j < 4; ++j)
          acc[i][j] = __builtin_amdgcn_mfma_f32_16x16x32_bf16(a[i], b[j], acc[i][j], 0, 0, 0);
    }
    __syncthreads();  // prefetch published (vmcnt drained), buf[cur] free
  }

  const int cn = lane & 15, cm = (lane >> 4) * 4;
#pragma unroll
  for (int j = 0; j < 4; ++j) {
    int n = gn0 + wn + j * 16 + cn;
    if (n < 1000) {
      float bv = bh[n];
#pragma unroll
      for (int i = 0; i < 4; ++i)
#pragma unroll
        for (int r = 0; r < 4; ++r) {
          int m = gm0 + wm + i * 16 + cm + r;
          out[(size_t)m * 1000 + n] = acc[i][j][r] + bv;
        }
    }
  }
}

// ---------- launch ----------
extern "C" void kernel_launch(void* const* d_in, const int* in_sizes, int n_in,
                              void* d_out, int out_size, void* d_ws, size_t ws_size,
                              hipStream_t stream) {
  const float* x = (const float*)d_in[0];        // [4096,1024]
  const float* centers = (const float*)d_in[1];  // [1024,16]
  const float* scales = (const float*)d_in[2];   // [1024,16]
  const float* Wb = (const float*)d_in[3];       // [16384,4096]
  const float* bb = (const float*)d_in[4];       // [4096]
  const float* Wh = (const float*)d_in[5];       // [4096,1000]
  const float* bh = (const float*)d_in[6];       // [1000]
  float* out = (float*)d_out;                    // [4096,1000]

  unsigned char* feats = (unsigned char*)d_ws;          // [4096][16384] fp8 (67 MB)
  unsigned char* Wbt = feats + (size_t)4096 * 16384;    // [4096][16384] fp8 (67 MB)
  __hip_bfloat16* phi = (__hip_bfloat16*)(Wbt + (size_t)4096 * 16384);  // 32 MB
  __hip_bfloat16* Wht = phi + (size_t)4096 * 4096;      // [1024][4096] bf16 (8 MB)

  feats_kernel<<<dim3(16384), dim3(256), 0, stream>>>(x, centers, scales, feats);
  // Wb [16384,4096] fp32 -> Wbt [4096][16384] fp8 (x128)
  transpose_fp8<<<dim3(64, 256), dim3(256), 0, stream>>>(Wb, Wbt, 16384, 4096);
  // Wh [4096,1000] -> Wht [1024][4096] bf16, rows 1000..1023 zero
  transpose_cast<<<dim3(16, 64), dim3(256), 0, stream>>>(Wh, Wht, 4096, 1000, 1024);
  // GEMM1: phi = sigmoid(feats @ Wb + bb)  (M=N=4096, K=16384), MX-fp8
  // 256x256 tiles, 8 waves, 32x32x64 MFMA, BK=64, 3-stage counted-vmcnt pipeline
  gemm1_mx32<<<dim3(256), dim3(512), 0, stream>>>(feats, Wbt, bb, phi, 4096, 4096, 16384);
  // GEMM2 fused: out = phi @ Wht + bh (full K, bias + n<1000 mask in epilogue)
  gemm2_full<<<dim3(8, 32), dim3(256), 0, stream>>>(phi, Wht, bh, out, 4096, 1024, 4096);
}

// Round 5
// 873.127 us; speedup vs baseline: 1.0105x; 1.0105x over previous
//
#include <hip/hip_runtime.h>
#include <hip/hip_bf16.h>

// ---------- types ----------
typedef __bf16 bf16x8_t __attribute__((ext_vector_type(8)));
typedef float f32x4_t __attribute__((ext_vector_type(4)));
typedef int i32x4_t __attribute__((ext_vector_type(4)));
typedef int i32x8_t __attribute__((ext_vector_type(8)));

#define GLDS(gp, lp) __builtin_amdgcn_global_load_lds(                        \
    (const __attribute__((address_space(1))) void*)(gp),                      \
    (__attribute__((address_space(3))) void*)(lp), 16, 0, 0)

// ---------- fast tanh ----------
__device__ __forceinline__ float fast_tanh(float z) {
  float zc = fminf(10.0f, fmaxf(-10.0f, z));
  float e = __expf(2.0f * zc);
  return 1.0f - 2.0f / (e + 1.0f);
}

// pack 4 floats -> 4 fp8 e4m3 bytes (HW cvt => matches MFMA format)
__device__ __forceinline__ int pack_fp8x4(float a, float b, float c, float d) {
  int w = __builtin_amdgcn_cvt_pk_fp8_f32(a, b, 0, false);
  w = __builtin_amdgcn_cvt_pk_fp8_f32(c, d, w, true);
  return w;
}

// ---------- 1) feats (fp8 e4m3): feats[b, d*16+k] = tanh((x-c)*s) ----------
__global__ __launch_bounds__(256) void feats_kernel(
    const float* __restrict__ x, const float* __restrict__ c,
    const float* __restrict__ s, unsigned char* __restrict__ out) {
  int idx = blockIdx.x * 256 + threadIdx.x;  // (b,d) pair; 4096*1024 total
  int d = idx & 1023;
  float xv = x[idx];
  const float4* c4 = (const float4*)(c + d * 16);
  const float4* s4 = (const float4*)(s + d * 16);
  int w[4];
#pragma unroll
  for (int g = 0; g < 4; ++g) {
    float4 cc = c4[g], ss = s4[g];
    float t0 = fast_tanh((xv - cc.x) * ss.x);
    float t1 = fast_tanh((xv - cc.y) * ss.y);
    float t2 = fast_tanh((xv - cc.z) * ss.z);
    float t3 = fast_tanh((xv - cc.w) * ss.w);
    w[g] = pack_fp8x4(t0, t1, t2, t3);
  }
  *(uint4*)(out + (size_t)idx * 16) = make_uint4(w[0], w[1], w[2], w[3]);
}

// ---------- 2) transpose+cast fp32 [R][C] -> fp8 [C][R] scaled by 128 ----------
__global__ __launch_bounds__(256) void transpose_fp8(
    const float* __restrict__ src, unsigned char* __restrict__ dst, int R, int C) {
  __shared__ float tile[64][65];
  const int c0 = blockIdx.x * 64, r0 = blockIdx.y * 64;
  const int t = threadIdx.x;
  const int rr = t >> 4, cc4 = (t & 15) * 4;
#pragma unroll
  for (int p = 0; p < 4; ++p) {
    int row = rr + p * 16;
    float4 v = *(const float4*)(src + (size_t)(r0 + row) * C + c0 + cc4);
    tile[row][cc4 + 0] = v.x;
    tile[row][cc4 + 1] = v.y;
    tile[row][cc4 + 2] = v.z;
    tile[row][cc4 + 3] = v.w;
  }
  __syncthreads();
  const int drow = t >> 2, seg = (t & 3) * 16;
  int w[4];
#pragma unroll
  for (int g = 0; g < 4; ++g) {
    float a = tile[seg + g * 4 + 0][drow] * 128.0f;
    float b = tile[seg + g * 4 + 1][drow] * 128.0f;
    float cc = tile[seg + g * 4 + 2][drow] * 128.0f;
    float d = tile[seg + g * 4 + 3][drow] * 128.0f;
    w[g] = pack_fp8x4(a, b, cc, d);
  }
  *(uint4*)(dst + (size_t)(c0 + drow) * R + r0 + seg) = make_uint4(w[0], w[1], w[2], w[3]);
}

// ---------- 3) transpose+cast fp32 [R][C] -> bf16 [Cpad][R], zero-fill ----------
__global__ __launch_bounds__(256) void transpose_cast(
    const float* __restrict__ src, __hip_bfloat16* __restrict__ dst,
    int R, int C, int Cpad) {
  __shared__ float tile[64][65];
  const int c0 = blockIdx.x * 64, r0 = blockIdx.y * 64;
  const int t = threadIdx.x;
  const int rr = t >> 4, cc4 = (t & 15) * 4;
#pragma unroll
  for (int p = 0; p < 4; ++p) {
    int row = rr + p * 16;
    int cbase = c0 + cc4;
    float4 v;
    if (cbase + 3 < C) {
      v = *(const float4*)(src + (size_t)(r0 + row) * C + cbase);
    } else {
      v.x = (cbase + 0 < C) ? src[(size_t)(r0 + row) * C + cbase + 0] : 0.0f;
      v.y = (cbase + 1 < C) ? src[(size_t)(r0 + row) * C + cbase + 1] : 0.0f;
      v.z = (cbase + 2 < C) ? src[(size_t)(r0 + row) * C + cbase + 2] : 0.0f;
      v.w = (cbase + 3 < C) ? src[(size_t)(r0 + row) * C + cbase + 3] : 0.0f;
    }
    tile[row][cc4 + 0] = v.x;
    tile[row][cc4 + 1] = v.y;
    tile[row][cc4 + 2] = v.z;
    tile[row][cc4 + 3] = v.w;
  }
  __syncthreads();
#pragma unroll
  for (int p = 0; p < 2; ++p) {
    int i = t + 256 * p;
    int drow = i >> 3;
    int seg = (i & 7) * 8;
    int dc = c0 + drow;
    alignas(16) __hip_bfloat16 vals[8];
#pragma unroll
    for (int j = 0; j < 8; ++j) vals[j] = __float2bfloat16(tile[seg + j][drow]);
    if (dc < Cpad)
      *(uint4*)(dst + (size_t)dc * R + r0 + seg) = *(const uint4*)vals;
  }
}

// ---------- 4) GEMM1: MX-fp8 16x16x128, 256x256 tile, 4-phase + counted vmcnt ----------
// A [M][K] fp8, Bt [N][K] fp8 (pre-scaled x128). XOR-swizzled LDS rows (128B):
// row r's 16B k-group g stored at slot g^(r&7); GLDS source pre-swizzled to match.
// Round-2 verified 4-phase body; single change: tile t+1's 8 GLDS issued at tile
// top, then s_waitcnt vmcnt(8) (tile t landed, t+1 in flight) -- vmcnt never
// drains to 0 in the main loop (T4). Trailing barrier is a plain s_barrier.
// out: phi[m*N+n] = bf16(sigmoid(acc/128 + bias[n]))
__global__ __launch_bounds__(512, 2) void gemm1_mx8(
    const unsigned char* __restrict__ A, const unsigned char* __restrict__ Bt,
    const float* __restrict__ bias, __hip_bfloat16* __restrict__ outb,
    int M, int N, int K) {
  __shared__ unsigned char As[2][256 * 128];  // 64 KB
  __shared__ unsigned char Bs[2][256 * 128];  // 64 KB
  const int tid = threadIdx.x;
  const int wave = tid >> 6, lane = tid & 63;
  const int wm = (wave >> 2) * 128, wn = (wave & 3) * 64;  // 2M x 4N waves

  // XCD swizzle (nwg=256, bijective) + 4x8 rectangle per XCD for L2 reuse
  const int bid = blockIdx.x;
  const int swz = (bid & 7) * 32 + (bid >> 3);
  const int gq = swz >> 5, u = swz & 31;
  const int gm0 = ((gq >> 1) * 4 + (u >> 3)) * 256;
  const int gn0 = ((gq & 1) * 8 + (u & 7)) * 256;

  // staging: chunk c (16B), c = p*512 + tid; lds byte c*16; row = c>>3;
  // stored slot sg = c&7 -> global k-group g = sg ^ (row&7)
  const unsigned char* ga[4];
  const unsigned char* gb[4];
  int ldso[4];
#pragma unroll
  for (int p = 0; p < 4; ++p) {
    int c = p * 512 + tid;
    int row = c >> 3;
    int g = (c & 7) ^ (row & 7);
    ga[p] = A + (size_t)(gm0 + row) * K + g * 16;
    gb[p] = Bt + (size_t)(gn0 + row) * K + g * 16;
    ldso[p] = c * 16;
  }

  f32x4_t acc[8][4] = {};
  const int fr = lane & 15, kh = lane >> 4;  // frag row; k-quarter (32B)

  // prologue: stage tile 0 into buffer 0 (no barrier; loop top waits)
#pragma unroll
  for (int p = 0; p < 4; ++p) {
    GLDS(ga[p], &As[0][ldso[p]]);
    GLDS(gb[p], &Bs[0][ldso[p]]);
  }

  const int NT = K >> 7;
  for (int t = 0; t < NT; ++t) {
    const unsigned char* Ac = As[t & 1];
    const unsigned char* Bc = Bs[t & 1];

    // issue tile t+1 prefetch into the other buffer (freed by the trailing
    // barrier of tile t-1), then wait ONLY for tile t's own 8 loads.
    if (t + 1 < NT) {
      unsigned char* An = (unsigned char*)As[(t + 1) & 1];
      unsigned char* Bn = (unsigned char*)Bs[(t + 1) & 1];
      const int k1 = (t + 1) << 7;
#pragma unroll
      for (int p = 0; p < 4; ++p) {
        GLDS(ga[p] + k1, An + ldso[p]);
        GLDS(gb[p] + k1, Bn + ldso[p]);
      }
      asm volatile("s_waitcnt vmcnt(8)" ::: "memory");
    } else {
      asm volatile("s_waitcnt vmcnt(0)" ::: "memory");
    }
    __builtin_amdgcn_s_barrier();      // all waves' tile-t loads landed
    __builtin_amdgcn_sched_barrier(0); // keep ds_reads below the barrier

    // b-frags: loaded once per K-tile, held live across all 4 phases
    i32x8_t b[4];
#pragma unroll
    for (int j = 0; j < 4; ++j) {
      int rb = wn + j * 16 + fr, sb = rb & 7;
      i32x4_t blo = *(const i32x4_t*)(Bc + rb * 128 + (((2 * kh) ^ sb) * 16));
      i32x4_t bhi = *(const i32x4_t*)(Bc + rb * 128 + (((2 * kh + 1) ^ sb) * 16));
      b[j] = __builtin_shufflevector(blo, bhi, 0, 1, 2, 3, 4, 5, 6, 7);
    }

#pragma unroll
    for (int p = 0; p < 4; ++p) {
      // a-frag pair for this phase
      i32x8_t a0, a1;
      {
        int ra = wm + (2 * p + 0) * 16 + fr, sa = ra & 7;
        i32x4_t lo = *(const i32x4_t*)(Ac + ra * 128 + (((2 * kh) ^ sa) * 16));
        i32x4_t hi = *(const i32x4_t*)(Ac + ra * 128 + (((2 * kh + 1) ^ sa) * 16));
        a0 = __builtin_shufflevector(lo, hi, 0, 1, 2, 3, 4, 5, 6, 7);
      }
      {
        int ra = wm + (2 * p + 1) * 16 + fr, sa = ra & 7;
        i32x4_t lo = *(const i32x4_t*)(Ac + ra * 128 + (((2 * kh) ^ sa) * 16));
        i32x4_t hi = *(const i32x4_t*)(Ac + ra * 128 + (((2 * kh + 1) ^ sa) * 16));
        a1 = __builtin_shufflevector(lo, hi, 0, 1, 2, 3, 4, 5, 6, 7);
      }
      __builtin_amdgcn_s_barrier();
      __builtin_amdgcn_s_setprio(1);
#pragma unroll
      for (int j = 0; j < 4; ++j) {
        acc[2 * p + 0][j] = __builtin_amdgcn_mfma_scale_f32_16x16x128_f8f6f4(
            a0, b[j], acc[2 * p + 0][j], 0, 0, 0, 0x7F7F7F7F, 0, 0x7F7F7F7F);
        acc[2 * p + 1][j] = __builtin_amdgcn_mfma_scale_f32_16x16x128_f8f6f4(
            a1, b[j], acc[2 * p + 1][j], 0, 0, 0, 0x7F7F7F7F, 0, 0x7F7F7F7F);
      }
      __builtin_amdgcn_s_setprio(0);
    }
    // trailing plain barrier: all waves done reading buf[t&1] before any wave's
    // next-iteration GLDS overwrites it. NO vmcnt drain here.
    __builtin_amdgcn_s_barrier();
  }

  // C/D: row = (lane>>4)*4 + reg, col = lane&15
  const int cn = lane & 15, cm = (lane >> 4) * 4;
#pragma unroll
  for (int j = 0; j < 4; ++j) {
    int n = gn0 + wn + j * 16 + cn;
    float bv = bias[n];
#pragma unroll
    for (int i = 0; i < 8; ++i) {
#pragma unroll
      for (int r = 0; r < 4; ++r) {
        int m = gm0 + wm + i * 16 + cm + r;
        float v = acc[i][j][r] * 0.0078125f + bv;  // /128 de-scale of Wb
        float phi = 1.0f / (1.0f + __expf(-v));
        outb[(size_t)m * N + n] = __float2bfloat16(phi);
      }
    }
  }
}

// ---------- 5) GEMM2 fused: full-K bf16, counted-vmcnt double-buffer ----------
// out[m, n] = phi[m,:] @ Wht[n,:] + bh[n]   for n < 1000; out row stride 1000.
__global__ __launch_bounds__(256) void gemm2_full(
    const __hip_bfloat16* __restrict__ A, const __hip_bfloat16* __restrict__ Bt,
    const float* __restrict__ bh, float* __restrict__ out,
    int M, int N, int K) {
  __shared__ __hip_bfloat16 As[2][2][128 * 32];  // dbuf x k-half, 32 KB
  __shared__ __hip_bfloat16 Bs[2][2][128 * 32];  // 32 KB
  const int tid = threadIdx.x;
  const int wave = tid >> 6, lane = tid & 63;
  const int wm = (wave >> 1) * 64, wn = (wave & 1) * 64;
  const int gm0 = blockIdx.y * 128, gn0 = blockIdx.x * 128;

  const int t1 = tid, t2 = tid + 256;
  const __hip_bfloat16* Ag0 = A + (size_t)(gm0 + (t1 >> 2)) * K + (t1 & 3) * 8;
  const __hip_bfloat16* Ag1 = A + (size_t)(gm0 + (t2 >> 2)) * K + (t2 & 3) * 8;
  const __hip_bfloat16* Bg0 = Bt + (size_t)(gn0 + (t1 >> 2)) * K + (t1 & 3) * 8;
  const __hip_bfloat16* Bg1 = Bt + (size_t)(gn0 + (t2 >> 2)) * K + (t2 & 3) * 8;

  f32x4_t acc[4][4] = {};
  const int fr = lane & 15, fk = (lane >> 4) * 8;

  // prologue: stage k-iter 0 into buf 0 (no barrier; loop top waits)
#pragma unroll
  for (int h = 0; h < 2; ++h) {
    GLDS(Ag0 + h * 32, &As[0][h][t1 * 8]);
    GLDS(Ag1 + h * 32, &As[0][h][t2 * 8]);
    GLDS(Bg0 + h * 32, &Bs[0][h][t1 * 8]);
    GLDS(Bg1 + h * 32, &Bs[0][h][t2 * 8]);
  }
  Ag0 += 64; Ag1 += 64; Bg0 += 64; Bg1 += 64;

  const int nk = K >> 6;
  for (int it = 0; it < nk; ++it) {
    const int cur = it & 1;
    if (it + 1 < nk) {
      const int nxt = cur ^ 1;
#pragma unroll
      for (int h = 0; h < 2; ++h) {
        GLDS(Ag0 + h * 32, &As[nxt][h][t1 * 8]);
        GLDS(Ag1 + h * 32, &As[nxt][h][t2 * 8]);
        GLDS(Bg0 + h * 32, &Bs[nxt][h][t1 * 8]);
        GLDS(Bg1 + h * 32, &Bs[nxt][h][t2 * 8]);
      }
      Ag0 += 64; Ag1 += 64; Bg0 += 64; Bg1 += 64;
      asm volatile("s_waitcnt vmcnt(8)" ::: "memory");  // iter it landed
    } else {
      asm volatile("s_waitcnt vmcnt(0)" ::: "memory");
    }
    __builtin_amdgcn_s_barrier();
    __builtin_amdgcn_sched_barrier(0);
#pragma unroll
    for (int h = 0; h < 2; ++h) {
      bf16x8_t a[4], b[4];
#pragma unroll
      for (int i = 0; i < 4; ++i) {
        a[i] = *(const bf16x8_t*)(&As[cur][h][(wm + i * 16 + fr) * 32 + fk]);
        b[i] = *(const bf16x8_t*)(&Bs[cur][h][(wn + i * 16 + fr) * 32 + fk]);
      }
#pragma unroll
      for (int i = 0; i < 4; ++i)
#pragma unroll
        for (int j = 0; j < 4; ++j)
          acc[i][j] = __builtin_amdgcn_mfma_f32_16x16x32_bf16(a[i], b[j], acc[i][j], 0, 0, 0);
    }
    __builtin_amdgcn_s_barrier();  // reads of buf[cur] done; no vmcnt drain
  }

  const int cn = lane & 15, cm = (lane >> 4) * 4;
#pragma unroll
  for (int j = 0; j < 4; ++j) {
    int n = gn0 + wn + j * 16 + cn;
    if (n < 1000) {
      float bv = bh[n];
#pragma unroll
      for (int i = 0; i < 4; ++i)
#pragma unroll
        for (int r = 0; r < 4; ++r) {
          int m = gm0 + wm + i * 16 + cm + r;
          out[(size_t)m * 1000 + n] = acc[i][j][r] + bv;
        }
    }
  }
}

// ---------- launch ----------
extern "C" void kernel_launch(void* const* d_in, const int* in_sizes, int n_in,
                              void* d_out, int out_size, void* d_ws, size_t ws_size,
                              hipStream_t stream) {
  const float* x = (const float*)d_in[0];        // [4096,1024]
  const float* centers = (const float*)d_in[1];  // [1024,16]
  const float* scales = (const float*)d_in[2];   // [1024,16]
  const float* Wb = (const float*)d_in[3];       // [16384,4096]
  const float* bb = (const float*)d_in[4];       // [4096]
  const float* Wh = (const float*)d_in[5];       // [4096,1000]
  const float* bh = (const float*)d_in[6];       // [1000]
  float* out = (float*)d_out;                    // [4096,1000]

  unsigned char* feats = (unsigned char*)d_ws;          // [4096][16384] fp8 (67 MB)
  unsigned char* Wbt = feats + (size_t)4096 * 16384;    // [4096][16384] fp8 (67 MB)
  __hip_bfloat16* phi = (__hip_bfloat16*)(Wbt + (size_t)4096 * 16384);  // 32 MB
  __hip_bfloat16* Wht = phi + (size_t)4096 * 4096;      // [1024][4096] bf16 (8 MB)

  feats_kernel<<<dim3(16384), dim3(256), 0, stream>>>(x, centers, scales, feats);
  // Wb [16384,4096] fp32 -> Wbt [4096][16384] fp8 (x128)
  transpose_fp8<<<dim3(64, 256), dim3(256), 0, stream>>>(Wb, Wbt, 16384, 4096);
  // Wh [4096,1000] -> Wht [1024][4096] bf16, rows 1000..1023 zero
  transpose_cast<<<dim3(16, 64), dim3(256), 0, stream>>>(Wh, Wht, 4096, 1000, 1024);
  // GEMM1: phi = sigmoid(feats @ Wb + bb)  (M=N=4096, K=16384), MX-fp8
  // 256x256 tiles, 8 waves, 4-phase body, counted-vmcnt double-buffer (T4)
  gemm1_mx8<<<dim3(256), dim3(512), 0, stream>>>(feats, Wbt, bb, phi, 4096, 4096, 16384);
  // GEMM2 fused: out = phi @ Wht + bh (full K, bias + n<1000 mask in epilogue)
  gemm2_full<<<dim3(8, 32), dim3(256), 0, stream>>>(phi, Wht, bh, out, 4096, 1024, 4096);
}

// Round 6
// 786.051 us; speedup vs baseline: 1.1225x; 1.1108x over previous
//
#include <hip/hip_runtime.h>
#include <hip/hip_bf16.h>

// ---------- types ----------
typedef __bf16 bf16x8_t __attribute__((ext_vector_type(8)));
typedef float f32x4_t __attribute__((ext_vector_type(4)));
typedef int i32x4_t __attribute__((ext_vector_type(4)));
typedef int i32x8_t __attribute__((ext_vector_type(8)));

#define GLDS(gp, lp) __builtin_amdgcn_global_load_lds(                        \
    (const __attribute__((address_space(1))) void*)(gp),                      \
    (__attribute__((address_space(3))) void*)(lp), 16, 0, 0)

// ---------- fast tanh ----------
__device__ __forceinline__ float fast_tanh(float z) {
  float zc = fminf(10.0f, fmaxf(-10.0f, z));
  float e = __expf(2.0f * zc);
  return 1.0f - 2.0f / (e + 1.0f);
}

// pack 4 floats -> 4 fp8 e4m3 bytes (HW cvt => matches MFMA format)
__device__ __forceinline__ int pack_fp8x4(float a, float b, float c, float d) {
  int w = __builtin_amdgcn_cvt_pk_fp8_f32(a, b, 0, false);
  w = __builtin_amdgcn_cvt_pk_fp8_f32(c, d, w, true);
  return w;
}

// ---------- 1) feats (fp8 e4m3): feats[b, d*16+k] = tanh((x-c)*s) ----------
__global__ __launch_bounds__(256) void feats_kernel(
    const float* __restrict__ x, const float* __restrict__ c,
    const float* __restrict__ s, unsigned char* __restrict__ out) {
  int idx = blockIdx.x * 256 + threadIdx.x;  // (b,d) pair; 4096*1024 total
  int d = idx & 1023;
  float xv = x[idx];
  const float4* c4 = (const float4*)(c + d * 16);
  const float4* s4 = (const float4*)(s + d * 16);
  int w[4];
#pragma unroll
  for (int g = 0; g < 4; ++g) {
    float4 cc = c4[g], ss = s4[g];
    float t0 = fast_tanh((xv - cc.x) * ss.x);
    float t1 = fast_tanh((xv - cc.y) * ss.y);
    float t2 = fast_tanh((xv - cc.z) * ss.z);
    float t3 = fast_tanh((xv - cc.w) * ss.w);
    w[g] = pack_fp8x4(t0, t1, t2, t3);
  }
  *(uint4*)(out + (size_t)idx * 16) = make_uint4(w[0], w[1], w[2], w[3]);
}

// ---------- 2) transpose+cast fp32 [R][C] -> fp8 [C][R] scaled by 128 ----------
__global__ __launch_bounds__(256) void transpose_fp8(
    const float* __restrict__ src, unsigned char* __restrict__ dst, int R, int C) {
  __shared__ float tile[64][65];
  const int c0 = blockIdx.x * 64, r0 = blockIdx.y * 64;
  const int t = threadIdx.x;
  const int rr = t >> 4, cc4 = (t & 15) * 4;
#pragma unroll
  for (int p = 0; p < 4; ++p) {
    int row = rr + p * 16;
    float4 v = *(const float4*)(src + (size_t)(r0 + row) * C + c0 + cc4);
    tile[row][cc4 + 0] = v.x;
    tile[row][cc4 + 1] = v.y;
    tile[row][cc4 + 2] = v.z;
    tile[row][cc4 + 3] = v.w;
  }
  __syncthreads();
  const int drow = t >> 2, seg = (t & 3) * 16;
  int w[4];
#pragma unroll
  for (int g = 0; g < 4; ++g) {
    float a = tile[seg + g * 4 + 0][drow] * 128.0f;
    float b = tile[seg + g * 4 + 1][drow] * 128.0f;
    float cc = tile[seg + g * 4 + 2][drow] * 128.0f;
    float d = tile[seg + g * 4 + 3][drow] * 128.0f;
    w[g] = pack_fp8x4(a, b, cc, d);
  }
  *(uint4*)(dst + (size_t)(c0 + drow) * R + r0 + seg) = make_uint4(w[0], w[1], w[2], w[3]);
}

// ---------- 3) transpose+cast fp32 [R][C] -> bf16 [Cpad][R], zero-fill ----------
__global__ __launch_bounds__(256) void transpose_cast(
    const float* __restrict__ src, __hip_bfloat16* __restrict__ dst,
    int R, int C, int Cpad) {
  __shared__ float tile[64][65];
  const int c0 = blockIdx.x * 64, r0 = blockIdx.y * 64;
  const int t = threadIdx.x;
  const int rr = t >> 4, cc4 = (t & 15) * 4;
#pragma unroll
  for (int p = 0; p < 4; ++p) {
    int row = rr + p * 16;
    int cbase = c0 + cc4;
    float4 v;
    if (cbase + 3 < C) {
      v = *(const float4*)(src + (size_t)(r0 + row) * C + cbase);
    } else {
      v.x = (cbase + 0 < C) ? src[(size_t)(r0 + row) * C + cbase + 0] : 0.0f;
      v.y = (cbase + 1 < C) ? src[(size_t)(r0 + row) * C + cbase + 1] : 0.0f;
      v.z = (cbase + 2 < C) ? src[(size_t)(r0 + row) * C + cbase + 2] : 0.0f;
      v.w = (cbase + 3 < C) ? src[(size_t)(r0 + row) * C + cbase + 3] : 0.0f;
    }
    tile[row][cc4 + 0] = v.x;
    tile[row][cc4 + 1] = v.y;
    tile[row][cc4 + 2] = v.z;
    tile[row][cc4 + 3] = v.w;
  }
  __syncthreads();
#pragma unroll
  for (int p = 0; p < 2; ++p) {
    int i = t + 256 * p;
    int drow = i >> 3;
    int seg = (i & 7) * 8;
    int dc = c0 + drow;
    alignas(16) __hip_bfloat16 vals[8];
#pragma unroll
    for (int j = 0; j < 8; ++j) vals[j] = __float2bfloat16(tile[seg + j][drow]);
    if (dc < Cpad)
      *(uint4*)(dst + (size_t)dc * R + r0 + seg) = *(const uint4*)vals;
  }
}

// ---------- 4) GEMM1: MX-fp8, 256x256 tile, 8 waves, 4-phase, a-frag pipelined ----------
// A [M][K] fp8, Bt [N][K] fp8 (pre-scaled x128). XOR-swizzled LDS rows (128B):
// row r's 16B k-group g stored at slot g^(r&7); GLDS source pre-swizzled to match.
// Round-2 champion schedule (GLDS spread per phase, barrier pairs, end-of-tile
// __syncthreads). ONE change: a-frag pair for phase p+1 is ds_read BEFORE the
// MFMA cluster of phase p (register pipeline) so MFMA waits on counted lgkmcnt
// for old reads instead of fresh ones -- LDS latency hides under MFMA.
// out: phi[m*N+n] = bf16(sigmoid(acc/128 + bias[n]))
__global__ __launch_bounds__(512, 2) void gemm1_mx8(
    const unsigned char* __restrict__ A, const unsigned char* __restrict__ Bt,
    const float* __restrict__ bias, __hip_bfloat16* __restrict__ outb,
    int M, int N, int K) {
  __shared__ unsigned char As[2][256 * 128];  // 64 KB
  __shared__ unsigned char Bs[2][256 * 128];  // 64 KB
  const int tid = threadIdx.x;
  const int wave = tid >> 6, lane = tid & 63;
  const int wm = (wave >> 2) * 128, wn = (wave & 3) * 64;  // 2M x 4N waves

  // XCD swizzle (nwg=256, bijective) + 4x8 rectangle per XCD for L2 reuse
  const int bid = blockIdx.x;
  const int swz = (bid & 7) * 32 + (bid >> 3);
  const int gq = swz >> 5, u = swz & 31;
  const int gm0 = ((gq >> 1) * 4 + (u >> 3)) * 256;
  const int gn0 = ((gq & 1) * 8 + (u & 7)) * 256;

  // staging: chunk c (16B), c = p*512 + tid; lds byte c*16; row = c>>3;
  // stored slot sg = c&7 -> global k-group g = sg ^ (row&7)
  const unsigned char* ga[4];
  const unsigned char* gb[4];
  int ldso[4];
#pragma unroll
  for (int p = 0; p < 4; ++p) {
    int c = p * 512 + tid;
    int row = c >> 3;
    int g = (c & 7) ^ (row & 7);
    ga[p] = A + (size_t)(gm0 + row) * K + g * 16;
    gb[p] = Bt + (size_t)(gn0 + row) * K + g * 16;
    ldso[p] = c * 16;
  }

  f32x4_t acc[8][4] = {};
  const int fr = lane & 15, kh = lane >> 4;  // frag row; k-quarter (32B)

  // prologue: stage tile 0 into buffer 0
#pragma unroll
  for (int p = 0; p < 4; ++p) {
    GLDS(ga[p], &As[0][ldso[p]]);
    GLDS(gb[p], &Bs[0][ldso[p]]);
  }
  __syncthreads();

  const int NT = K >> 7;
  for (int t = 0; t < NT; ++t) {
    const unsigned char* Ac = As[t & 1];
    const unsigned char* Bc = Bs[t & 1];
    unsigned char* An = (unsigned char*)As[(t + 1) & 1];
    unsigned char* Bn = (unsigned char*)Bs[(t + 1) & 1];
    const int k1 = (t + 1) << 7;
    const bool pre = (t + 1 < NT);

    // b-frags: loaded once per K-tile, held live across all 4 phases
    i32x8_t b[4];
#pragma unroll
    for (int j = 0; j < 4; ++j) {
      int rb = wn + j * 16 + fr, sb = rb & 7;
      i32x4_t blo = *(const i32x4_t*)(Bc + rb * 128 + (((2 * kh) ^ sb) * 16));
      i32x4_t bhi = *(const i32x4_t*)(Bc + rb * 128 + (((2 * kh + 1) ^ sb) * 16));
      b[j] = __builtin_shufflevector(blo, bhi, 0, 1, 2, 3, 4, 5, 6, 7);
    }

    // a-pair for phase 0 (register pipeline head)
    i32x8_t a0, a1;
    {
      int ra = wm + 0 * 16 + fr, sa = ra & 7;
      i32x4_t lo = *(const i32x4_t*)(Ac + ra * 128 + (((2 * kh) ^ sa) * 16));
      i32x4_t hi = *(const i32x4_t*)(Ac + ra * 128 + (((2 * kh + 1) ^ sa) * 16));
      a0 = __builtin_shufflevector(lo, hi, 0, 1, 2, 3, 4, 5, 6, 7);
    }
    {
      int ra = wm + 1 * 16 + fr, sa = ra & 7;
      i32x4_t lo = *(const i32x4_t*)(Ac + ra * 128 + (((2 * kh) ^ sa) * 16));
      i32x4_t hi = *(const i32x4_t*)(Ac + ra * 128 + (((2 * kh + 1) ^ sa) * 16));
      a1 = __builtin_shufflevector(lo, hi, 0, 1, 2, 3, 4, 5, 6, 7);
    }

#pragma unroll
    for (int p = 0; p < 4; ++p) {
      // spread prefetch of tile t+1: one A-chunk + one B-chunk per phase
      if (pre) {
        GLDS(ga[p] + k1, An + ldso[p]);
        GLDS(gb[p] + k1, Bn + ldso[p]);
      }
      __builtin_amdgcn_s_barrier();

      // read a-pair for NEXT phase before this phase's MFMA cluster
      i32x8_t na0, na1;
      if (p < 3) {
        {
          int ra = wm + (2 * p + 2) * 16 + fr, sa = ra & 7;
          i32x4_t lo = *(const i32x4_t*)(Ac + ra * 128 + (((2 * kh) ^ sa) * 16));
          i32x4_t hi = *(const i32x4_t*)(Ac + ra * 128 + (((2 * kh + 1) ^ sa) * 16));
          na0 = __builtin_shufflevector(lo, hi, 0, 1, 2, 3, 4, 5, 6, 7);
        }
        {
          int ra = wm + (2 * p + 3) * 16 + fr, sa = ra & 7;
          i32x4_t lo = *(const i32x4_t*)(Ac + ra * 128 + (((2 * kh) ^ sa) * 16));
          i32x4_t hi = *(const i32x4_t*)(Ac + ra * 128 + (((2 * kh + 1) ^ sa) * 16));
          na1 = __builtin_shufflevector(lo, hi, 0, 1, 2, 3, 4, 5, 6, 7);
        }
      }

      __builtin_amdgcn_s_setprio(1);
#pragma unroll
      for (int j = 0; j < 4; ++j) {
        acc[2 * p + 0][j] = __builtin_amdgcn_mfma_scale_f32_16x16x128_f8f6f4(
            a0, b[j], acc[2 * p + 0][j], 0, 0, 0, 0x7F7F7F7F, 0, 0x7F7F7F7F);
        acc[2 * p + 1][j] = __builtin_amdgcn_mfma_scale_f32_16x16x128_f8f6f4(
            a1, b[j], acc[2 * p + 1][j], 0, 0, 0, 0x7F7F7F7F, 0, 0x7F7F7F7F);
      }
      __builtin_amdgcn_s_setprio(0);
      if (p < 3) {
        a0 = na0;
        a1 = na1;
        __builtin_amdgcn_s_barrier();
      }
    }
    // publish tile t+1 (drains vmcnt for the GLDS prefetch) + free buf[t&1]
    __syncthreads();
  }

  // C/D: row = (lane>>4)*4 + reg, col = lane&15
  const int cn = lane & 15, cm = (lane >> 4) * 4;
#pragma unroll
  for (int j = 0; j < 4; ++j) {
    int n = gn0 + wn + j * 16 + cn;
    float bv = bias[n];
#pragma unroll
    for (int i = 0; i < 8; ++i) {
#pragma unroll
      for (int r = 0; r < 4; ++r) {
        int m = gm0 + wm + i * 16 + cm + r;
        float v = acc[i][j][r] * 0.0078125f + bv;  // /128 de-scale of Wb
        float phi = 1.0f / (1.0f + __expf(-v));
        outb[(size_t)m * N + n] = __float2bfloat16(phi);
      }
    }
  }
}

// ---------- 5) GEMM2 fused: full-K bf16, cross-iter double-buffer, bias+mask ----------
// out[m, n] = phi[m,:] @ Wht[n,:] + bh[n]   for n < 1000; out row stride 1000.
__global__ __launch_bounds__(256) void gemm2_full(
    const __hip_bfloat16* __restrict__ A, const __hip_bfloat16* __restrict__ Bt,
    const float* __restrict__ bh, float* __restrict__ out,
    int M, int N, int K) {
  __shared__ __hip_bfloat16 As[2][2][128 * 32];  // dbuf x k-half, 32 KB
  __shared__ __hip_bfloat16 Bs[2][2][128 * 32];  // 32 KB
  const int tid = threadIdx.x;
  const int wave = tid >> 6, lane = tid & 63;
  const int wm = (wave >> 1) * 64, wn = (wave & 1) * 64;
  const int gm0 = blockIdx.y * 128, gn0 = blockIdx.x * 128;

  const int t1 = tid, t2 = tid + 256;
  const __hip_bfloat16* Ag0 = A + (size_t)(gm0 + (t1 >> 2)) * K + (t1 & 3) * 8;
  const __hip_bfloat16* Ag1 = A + (size_t)(gm0 + (t2 >> 2)) * K + (t2 & 3) * 8;
  const __hip_bfloat16* Bg0 = Bt + (size_t)(gn0 + (t1 >> 2)) * K + (t1 & 3) * 8;
  const __hip_bfloat16* Bg1 = Bt + (size_t)(gn0 + (t2 >> 2)) * K + (t2 & 3) * 8;

  f32x4_t acc[4][4] = {};
  const int fr = lane & 15, fk = (lane >> 4) * 8;

  // prologue: stage k-iter 0 into buf 0
#pragma unroll
  for (int h = 0; h < 2; ++h) {
    GLDS(Ag0 + h * 32, &As[0][h][t1 * 8]);
    GLDS(Ag1 + h * 32, &As[0][h][t2 * 8]);
    GLDS(Bg0 + h * 32, &Bs[0][h][t1 * 8]);
    GLDS(Bg1 + h * 32, &Bs[0][h][t2 * 8]);
  }
  Ag0 += 64; Ag1 += 64; Bg0 += 64; Bg1 += 64;
  __syncthreads();

  const int nk = K >> 6;
  for (int it = 0; it < nk; ++it) {
    const int cur = it & 1;
    if (it + 1 < nk) {
      const int nxt = cur ^ 1;
#pragma unroll
      for (int h = 0; h < 2; ++h) {
        GLDS(Ag0 + h * 32, &As[nxt][h][t1 * 8]);
        GLDS(Ag1 + h * 32, &As[nxt][h][t2 * 8]);
        GLDS(Bg0 + h * 32, &Bs[nxt][h][t1 * 8]);
        GLDS(Bg1 + h * 32, &Bs[nxt][h][t2 * 8]);
      }
      Ag0 += 64; Ag1 += 64; Bg0 += 64; Bg1 += 64;
    }
#pragma unroll
    for (int h = 0; h < 2; ++h) {
      bf16x8_t a[4], b[4];
#pragma unroll
      for (int i = 0; i < 4; ++i) {
        a[i] = *(const bf16x8_t*)(&As[cur][h][(wm + i * 16 + fr) * 32 + fk]);
        b[i] = *(const bf16x8_t*)(&Bs[cur][h][(wn + i * 16 + fr) * 32 + fk]);
      }
#pragma unroll
      for (int i = 0; i < 4; ++i)
#pragma unroll
        for (int j = 0; j < 4; ++j)
          acc[i][j] = __builtin_amdgcn_mfma_f32_16x16x32_bf16(a[i], b[j], acc[i][j], 0, 0, 0);
    }
    __syncthreads();  // prefetch published (vmcnt drained), buf[cur] free
  }

  const int cn = lane & 15, cm = (lane >> 4) * 4;
#pragma unroll
  for (int j = 0; j < 4; ++j) {
    int n = gn0 + wn + j * 16 + cn;
    if (n < 1000) {
      float bv = bh[n];
#pragma unroll
      for (int i = 0; i < 4; ++i)
#pragma unroll
        for (int r = 0; r < 4; ++r) {
          int m = gm0 + wm + i * 16 + cm + r;
          out[(size_t)m * 1000 + n] = acc[i][j][r] + bv;
        }
    }
  }
}

// ---------- launch ----------
extern "C" void kernel_launch(void* const* d_in, const int* in_sizes, int n_in,
                              void* d_out, int out_size, void* d_ws, size_t ws_size,
                              hipStream_t stream) {
  const float* x = (const float*)d_in[0];        // [4096,1024]
  const float* centers = (const float*)d_in[1];  // [1024,16]
  const float* scales = (const float*)d_in[2];   // [1024,16]
  const float* Wb = (const float*)d_in[3];       // [16384,4096]
  const float* bb = (const float*)d_in[4];       // [4096]
  const float* Wh = (const float*)d_in[5];       // [4096,1000]
  const float* bh = (const float*)d_in[6];       // [1000]
  float* out = (float*)d_out;                    // [4096,1000]

  unsigned char* feats = (unsigned char*)d_ws;          // [4096][16384] fp8 (67 MB)
  unsigned char* Wbt = feats + (size_t)4096 * 16384;    // [4096][16384] fp8 (67 MB)
  __hip_bfloat16* phi = (__hip_bfloat16*)(Wbt + (size_t)4096 * 16384);  // 32 MB
  __hip_bfloat16* Wht = phi + (size_t)4096 * 4096;      // [1024][4096] bf16 (8 MB)

  feats_kernel<<<dim3(16384), dim3(256), 0, stream>>>(x, centers, scales, feats);
  // Wb [16384,4096] fp32 -> Wbt [4096][16384] fp8 (x128)
  transpose_fp8<<<dim3(64, 256), dim3(256), 0, stream>>>(Wb, Wbt, 16384, 4096);
  // Wh [4096,1000] -> Wht [1024][4096] bf16, rows 1000..1023 zero
  transpose_cast<<<dim3(16, 64), dim3(256), 0, stream>>>(Wh, Wht, 4096, 1000, 1024);
  // GEMM1: phi = sigmoid(feats @ Wb + bb)  (M=N=4096, K=16384), MX-fp8
  // 256x256 tiles, 8 waves, round-2 schedule + a-frag register pipeline
  gemm1_mx8<<<dim3(256), dim3(512), 0, stream>>>(feats, Wbt, bb, phi, 4096, 4096, 16384);
  // GEMM2 fused: out = phi @ Wht + bh (full K, bias + n<1000 mask in epilogue)
  gemm2_full<<<dim3(8, 32), dim3(256), 0, stream>>>(phi, Wht, bh, out, 4096, 1024, 4096);
}

// Round 7
// 766.013 us; speedup vs baseline: 1.1518x; 1.0262x over previous
//
#include <hip/hip_runtime.h>
#include <hip/hip_bf16.h>

// ---------- types ----------
typedef __bf16 bf16x8_t __attribute__((ext_vector_type(8)));
typedef float f32x4_t __attribute__((ext_vector_type(4)));
typedef int i32x4_t __attribute__((ext_vector_type(4)));
typedef int i32x8_t __attribute__((ext_vector_type(8)));

#define GLDS(gp, lp) __builtin_amdgcn_global_load_lds(                        \
    (const __attribute__((address_space(1))) void*)(gp),                      \
    (__attribute__((address_space(3))) void*)(lp), 16, 0, 0)

// ---------- fast tanh ----------
__device__ __forceinline__ float fast_tanh(float z) {
  float zc = fminf(10.0f, fmaxf(-10.0f, z));
  float e = __expf(2.0f * zc);
  return 1.0f - 2.0f / (e + 1.0f);
}

// pack 4 floats -> 4 fp8 e4m3 bytes (HW cvt => matches MFMA format)
__device__ __forceinline__ int pack_fp8x4(float a, float b, float c, float d) {
  int w = __builtin_amdgcn_cvt_pk_fp8_f32(a, b, 0, false);
  w = __builtin_amdgcn_cvt_pk_fp8_f32(c, d, w, true);
  return w;
}

// ---------- 1) feats (fp8 e4m3): feats[b, d*16+k] = tanh((x-c)*s) ----------
__global__ __launch_bounds__(256) void feats_kernel(
    const float* __restrict__ x, const float* __restrict__ c,
    const float* __restrict__ s, unsigned char* __restrict__ out) {
  int idx = blockIdx.x * 256 + threadIdx.x;  // (b,d) pair; 4096*1024 total
  int d = idx & 1023;
  float xv = x[idx];
  const float4* c4 = (const float4*)(c + d * 16);
  const float4* s4 = (const float4*)(s + d * 16);
  int w[4];
#pragma unroll
  for (int g = 0; g < 4; ++g) {
    float4 cc = c4[g], ss = s4[g];
    float t0 = fast_tanh((xv - cc.x) * ss.x);
    float t1 = fast_tanh((xv - cc.y) * ss.y);
    float t2 = fast_tanh((xv - cc.z) * ss.z);
    float t3 = fast_tanh((xv - cc.w) * ss.w);
    w[g] = pack_fp8x4(t0, t1, t2, t3);
  }
  *(uint4*)(out + (size_t)idx * 16) = make_uint4(w[0], w[1], w[2], w[3]);
}

// ---------- 2) transpose+cast fp32 [R][C] -> fp8 [C][R] scaled by 128 ----------
// v2: 128R x 64C tiles. Reads 256-B contiguous segments; writes 128-B
// contiguous segments (4 thr x 32 B per dst row). LDS fp32 [128][65]
// (65 = +1 pad, conflict-free column reads). 33 KB LDS -> 4 blocks/CU.
__global__ __launch_bounds__(256) void transpose_fp8(
    const float* __restrict__ src, unsigned char* __restrict__ dst, int R, int C) {
  __shared__ float tile[128][65];
  const int c0 = blockIdx.x * 64, r0 = blockIdx.y * 128;
  const int t = threadIdx.x;
  // read: row = (t>>4) + 16q, float4-col = t&15 (64 floats/row)
  const int rr = t >> 4, fc = (t & 15) * 4;
#pragma unroll
  for (int q = 0; q < 8; ++q) {
    int row = rr + q * 16;
    float4 v = *(const float4*)(src + (size_t)(r0 + row) * C + c0 + fc);
    tile[row][fc + 0] = v.x;
    tile[row][fc + 1] = v.y;
    tile[row][fc + 2] = v.z;
    tile[row][fc + 3] = v.w;
  }
  __syncthreads();
  // write: dst row c = t>>2 (64 rows), bytes rbase..rbase+31 (rows of src)
  const int cc = t >> 2, rbase = (t & 3) * 32;
  int w[8];
#pragma unroll
  for (int g = 0; g < 8; ++g) {
    float a = tile[rbase + g * 4 + 0][cc] * 128.0f;
    float b = tile[rbase + g * 4 + 1][cc] * 128.0f;
    float c2 = tile[rbase + g * 4 + 2][cc] * 128.0f;
    float d = tile[rbase + g * 4 + 3][cc] * 128.0f;
    w[g] = pack_fp8x4(a, b, c2, d);
  }
  unsigned char* dp = dst + (size_t)(c0 + cc) * R + r0 + rbase;
  *(uint4*)(dp + 0) = make_uint4(w[0], w[1], w[2], w[3]);
  *(uint4*)(dp + 16) = make_uint4(w[4], w[5], w[6], w[7]);
}

// ---------- 3) transpose+cast fp32 [R][C] -> bf16 [Cpad][R], zero-fill ----------
__global__ __launch_bounds__(256) void transpose_cast(
    const float* __restrict__ src, __hip_bfloat16* __restrict__ dst,
    int R, int C, int Cpad) {
  __shared__ float tile[64][65];
  const int c0 = blockIdx.x * 64, r0 = blockIdx.y * 64;
  const int t = threadIdx.x;
  const int rr = t >> 4, cc4 = (t & 15) * 4;
#pragma unroll
  for (int p = 0; p < 4; ++p) {
    int row = rr + p * 16;
    int cbase = c0 + cc4;
    float4 v;
    if (cbase + 3 < C) {
      v = *(const float4*)(src + (size_t)(r0 + row) * C + cbase);
    } else {
      v.x = (cbase + 0 < C) ? src[(size_t)(r0 + row) * C + cbase + 0] : 0.0f;
      v.y = (cbase + 1 < C) ? src[(size_t)(r0 + row) * C + cbase + 1] : 0.0f;
      v.z = (cbase + 2 < C) ? src[(size_t)(r0 + row) * C + cbase + 2] : 0.0f;
      v.w = (cbase + 3 < C) ? src[(size_t)(r0 + row) * C + cbase + 3] : 0.0f;
    }
    tile[row][cc4 + 0] = v.x;
    tile[row][cc4 + 1] = v.y;
    tile[row][cc4 + 2] = v.z;
    tile[row][cc4 + 3] = v.w;
  }
  __syncthreads();
#pragma unroll
  for (int p = 0; p < 2; ++p) {
    int i = t + 256 * p;
    int drow = i >> 3;
    int seg = (i & 7) * 8;
    int dc = c0 + drow;
    alignas(16) __hip_bfloat16 vals[8];
#pragma unroll
    for (int j = 0; j < 8; ++j) vals[j] = __float2bfloat16(tile[seg + j][drow]);
    if (dc < Cpad)
      *(uint4*)(dst + (size_t)dc * R + r0 + seg) = *(const uint4*)vals;
  }
}

// ---------- 4) GEMM1: MX-fp8, 256x256 tile, 8 waves, 4-phase (round-2 body) ----------
// A [M][K] fp8, Bt [N][K] fp8 (pre-scaled x128). XOR-swizzled LDS rows (128B):
// row r's 16B k-group g stored at slot g^(r&7); GLDS source pre-swizzled to match.
// Round-2 champion schedule; only change: GLDS prefetch distributed 3/3/2/0
// across phases 0-2 so the last loads get >=2 phases of slack before the
// end-of-tile __syncthreads drain.
// out: phi[m*N+n] = bf16(sigmoid(acc/128 + bias[n]))
__global__ __launch_bounds__(512, 2) void gemm1_mx8(
    const unsigned char* __restrict__ A, const unsigned char* __restrict__ Bt,
    const float* __restrict__ bias, __hip_bfloat16* __restrict__ outb,
    int M, int N, int K) {
  __shared__ unsigned char As[2][256 * 128];  // 64 KB
  __shared__ unsigned char Bs[2][256 * 128];  // 64 KB
  const int tid = threadIdx.x;
  const int wave = tid >> 6, lane = tid & 63;
  const int wm = (wave >> 2) * 128, wn = (wave & 3) * 64;  // 2M x 4N waves

  // XCD swizzle (nwg=256, bijective) + 4x8 rectangle per XCD for L2 reuse
  const int bid = blockIdx.x;
  const int swz = (bid & 7) * 32 + (bid >> 3);
  const int gq = swz >> 5, u = swz & 31;
  const int gm0 = ((gq >> 1) * 4 + (u >> 3)) * 256;
  const int gn0 = ((gq & 1) * 8 + (u & 7)) * 256;

  // staging: chunk c (16B), c = p*512 + tid; lds byte c*16; row = c>>3;
  // stored slot sg = c&7 -> global k-group g = sg ^ (row&7)
  const unsigned char* ga[4];
  const unsigned char* gb[4];
  int ldso[4];
#pragma unroll
  for (int p = 0; p < 4; ++p) {
    int c = p * 512 + tid;
    int row = c >> 3;
    int g = (c & 7) ^ (row & 7);
    ga[p] = A + (size_t)(gm0 + row) * K + g * 16;
    gb[p] = Bt + (size_t)(gn0 + row) * K + g * 16;
    ldso[p] = c * 16;
  }

  f32x4_t acc[8][4] = {};
  const int fr = lane & 15, kh = lane >> 4;  // frag row; k-quarter (32B)

  // prologue: stage tile 0 into buffer 0
#pragma unroll
  for (int p = 0; p < 4; ++p) {
    GLDS(ga[p], &As[0][ldso[p]]);
    GLDS(gb[p], &Bs[0][ldso[p]]);
  }
  __syncthreads();

  const int NT = K >> 7;
  for (int t = 0; t < NT; ++t) {
    const unsigned char* Ac = As[t & 1];
    const unsigned char* Bc = Bs[t & 1];
    unsigned char* An = (unsigned char*)As[(t + 1) & 1];
    unsigned char* Bn = (unsigned char*)Bs[(t + 1) & 1];
    const int k1 = (t + 1) << 7;
    const bool pre = (t + 1 < NT);

    // b-frags: loaded once per K-tile, held live across all 4 phases
    i32x8_t b[4];
#pragma unroll
    for (int j = 0; j < 4; ++j) {
      int rb = wn + j * 16 + fr, sb = rb & 7;
      i32x4_t blo = *(const i32x4_t*)(Bc + rb * 128 + (((2 * kh) ^ sb) * 16));
      i32x4_t bhi = *(const i32x4_t*)(Bc + rb * 128 + (((2 * kh + 1) ^ sb) * 16));
      b[j] = __builtin_shufflevector(blo, bhi, 0, 1, 2, 3, 4, 5, 6, 7);
    }

#pragma unroll
    for (int p = 0; p < 4; ++p) {
      // prefetch of tile t+1: 3/3/2/0 over phases 0-2 (last loads get slack)
      if (pre) {
        if (p == 0) {
          GLDS(ga[0] + k1, An + ldso[0]);
          GLDS(gb[0] + k1, Bn + ldso[0]);
          GLDS(ga[2] + k1, An + ldso[2]);
        } else if (p == 1) {
          GLDS(gb[2] + k1, Bn + ldso[2]);
          GLDS(ga[1] + k1, An + ldso[1]);
          GLDS(gb[1] + k1, Bn + ldso[1]);
        } else if (p == 2) {
          GLDS(ga[3] + k1, An + ldso[3]);
          GLDS(gb[3] + k1, Bn + ldso[3]);
        }
      }
      // a-frag pair for this phase
      i32x8_t a0, a1;
      {
        int ra = wm + (2 * p + 0) * 16 + fr, sa = ra & 7;
        i32x4_t lo = *(const i32x4_t*)(Ac + ra * 128 + (((2 * kh) ^ sa) * 16));
        i32x4_t hi = *(const i32x4_t*)(Ac + ra * 128 + (((2 * kh + 1) ^ sa) * 16));
        a0 = __builtin_shufflevector(lo, hi, 0, 1, 2, 3, 4, 5, 6, 7);
      }
      {
        int ra = wm + (2 * p + 1) * 16 + fr, sa = ra & 7;
        i32x4_t lo = *(const i32x4_t*)(Ac + ra * 128 + (((2 * kh) ^ sa) * 16));
        i32x4_t hi = *(const i32x4_t*)(Ac + ra * 128 + (((2 * kh + 1) ^ sa) * 16));
        a1 = __builtin_shufflevector(lo, hi, 0, 1, 2, 3, 4, 5, 6, 7);
      }
      __builtin_amdgcn_s_barrier();
      __builtin_amdgcn_s_setprio(1);
#pragma unroll
      for (int j = 0; j < 4; ++j) {
        acc[2 * p + 0][j] = __builtin_amdgcn_mfma_scale_f32_16x16x128_f8f6f4(
            a0, b[j], acc[2 * p + 0][j], 0, 0, 0, 0x7F7F7F7F, 0, 0x7F7F7F7F);
        acc[2 * p + 1][j] = __builtin_amdgcn_mfma_scale_f32_16x16x128_f8f6f4(
            a1, b[j], acc[2 * p + 1][j], 0, 0, 0, 0x7F7F7F7F, 0, 0x7F7F7F7F);
      }
      __builtin_amdgcn_s_setprio(0);
      if (p < 3) __builtin_amdgcn_s_barrier();
    }
    // publish tile t+1 (drains vmcnt for the GLDS prefetch) + free buf[t&1]
    __syncthreads();
  }

  // C/D: row = (lane>>4)*4 + reg, col = lane&15
  const int cn = lane & 15, cm = (lane >> 4) * 4;
#pragma unroll
  for (int j = 0; j < 4; ++j) {
    int n = gn0 + wn + j * 16 + cn;
    float bv = bias[n];
#pragma unroll
    for (int i = 0; i < 8; ++i) {
#pragma unroll
      for (int r = 0; r < 4; ++r) {
        int m = gm0 + wm + i * 16 + cm + r;
        float v = acc[i][j][r] * 0.0078125f + bv;  // /128 de-scale of Wb
        float phi = 1.0f / (1.0f + __expf(-v));
        outb[(size_t)m * N + n] = __float2bfloat16(phi);
      }
    }
  }
}

// ---------- 5) GEMM2 fused: full-K bf16, cross-iter double-buffer, bias+mask ----------
// out[m, n] = phi[m,:] @ Wht[n,:] + bh[n]   for n < 1000; out row stride 1000.
__global__ __launch_bounds__(256) void gemm2_full(
    const __hip_bfloat16* __restrict__ A, const __hip_bfloat16* __restrict__ Bt,
    const float* __restrict__ bh, float* __restrict__ out,
    int M, int N, int K) {
  __shared__ __hip_bfloat16 As[2][2][128 * 32];  // dbuf x k-half, 32 KB
  __shared__ __hip_bfloat16 Bs[2][2][128 * 32];  // 32 KB
  const int tid = threadIdx.x;
  const int wave = tid >> 6, lane = tid & 63;
  const int wm = (wave >> 1) * 64, wn = (wave & 1) * 64;
  const int gm0 = blockIdx.y * 128, gn0 = blockIdx.x * 128;

  const int t1 = tid, t2 = tid + 256;
  const __hip_bfloat16* Ag0 = A + (size_t)(gm0 + (t1 >> 2)) * K + (t1 & 3) * 8;
  const __hip_bfloat16* Ag1 = A + (size_t)(gm0 + (t2 >> 2)) * K + (t2 & 3) * 8;
  const __hip_bfloat16* Bg0 = Bt + (size_t)(gn0 + (t1 >> 2)) * K + (t1 & 3) * 8;
  const __hip_bfloat16* Bg1 = Bt + (size_t)(gn0 + (t2 >> 2)) * K + (t2 & 3) * 8;

  f32x4_t acc[4][4] = {};
  const int fr = lane & 15, fk = (lane >> 4) * 8;

  // prologue: stage k-iter 0 into buf 0
#pragma unroll
  for (int h = 0; h < 2; ++h) {
    GLDS(Ag0 + h * 32, &As[0][h][t1 * 8]);
    GLDS(Ag1 + h * 32, &As[0][h][t2 * 8]);
    GLDS(Bg0 + h * 32, &Bs[0][h][t1 * 8]);
    GLDS(Bg1 + h * 32, &Bs[0][h][t2 * 8]);
  }
  Ag0 += 64; Ag1 += 64; Bg0 += 64; Bg1 += 64;
  __syncthreads();

  const int nk = K >> 6;
  for (int it = 0; it < nk; ++it) {
    const int cur = it & 1;
    if (it + 1 < nk) {
      const int nxt = cur ^ 1;
#pragma unroll
      for (int h = 0; h < 2; ++h) {
        GLDS(Ag0 + h * 32, &As[nxt][h][t1 * 8]);
        GLDS(Ag1 + h * 32, &As[nxt][h][t2 * 8]);
        GLDS(Bg0 + h * 32, &Bs[nxt][h][t1 * 8]);
        GLDS(Bg1 + h * 32, &Bs[nxt][h][t2 * 8]);
      }
      Ag0 += 64; Ag1 += 64; Bg0 += 64; Bg1 += 64;
    }
#pragma unroll
    for (int h = 0; h < 2; ++h) {
      bf16x8_t a[4], b[4];
#pragma unroll
      for (int i = 0; i < 4; ++i) {
        a[i] = *(const bf16x8_t*)(&As[cur][h][(wm + i * 16 + fr) * 32 + fk]);
        b[i] = *(const bf16x8_t*)(&Bs[cur][h][(wn + i * 16 + fr) * 32 + fk]);
      }
#pragma unroll
      for (int i = 0; i < 4; ++i)
#pragma unroll
        for (int j = 0; j < 4; ++j)
          acc[i][j] = __builtin_amdgcn_mfma_f32_16x16x32_bf16(a[i], b[j], acc[i][j], 0, 0, 0);
    }
    __syncthreads();  // prefetch published (vmcnt drained), buf[cur] free
  }

  const int cn = lane & 15, cm = (lane >> 4) * 4;
#pragma unroll
  for (int j = 0; j < 4; ++j) {
    int n = gn0 + wn + j * 16 + cn;
    if (n < 1000) {
      float bv = bh[n];
#pragma unroll
      for (int i = 0; i < 4; ++i)
#pragma unroll
        for (int r = 0; r < 4; ++r) {
          int m = gm0 + wm + i * 16 + cm + r;
          out[(size_t)m * 1000 + n] = acc[i][j][r] + bv;
        }
    }
  }
}

// ---------- launch ----------
extern "C" void kernel_launch(void* const* d_in, const int* in_sizes, int n_in,
                              void* d_out, int out_size, void* d_ws, size_t ws_size,
                              hipStream_t stream) {
  const float* x = (const float*)d_in[0];        // [4096,1024]
  const float* centers = (const float*)d_in[1];  // [1024,16]
  const float* scales = (const float*)d_in[2];   // [1024,16]
  const float* Wb = (const float*)d_in[3];       // [16384,4096]
  const float* bb = (const float*)d_in[4];       // [4096]
  const float* Wh = (const float*)d_in[5];       // [4096,1000]
  const float* bh = (const float*)d_in[6];       // [1000]
  float* out = (float*)d_out;                    // [4096,1000]

  unsigned char* feats = (unsigned char*)d_ws;          // [4096][16384] fp8 (67 MB)
  unsigned char* Wbt = feats + (size_t)4096 * 16384;    // [4096][16384] fp8 (67 MB)
  __hip_bfloat16* phi = (__hip_bfloat16*)(Wbt + (size_t)4096 * 16384);  // 32 MB
  __hip_bfloat16* Wht = phi + (size_t)4096 * 4096;      // [1024][4096] bf16 (8 MB)

  feats_kernel<<<dim3(16384), dim3(256), 0, stream>>>(x, centers, scales, feats);
  // Wb [16384,4096] fp32 -> Wbt [4096][16384] fp8 (x128); 128Rx64C tiles,
  // 256-B coalesced reads, 128-B coalesced writes
  transpose_fp8<<<dim3(64, 128), dim3(256), 0, stream>>>(Wb, Wbt, 16384, 4096);
  // Wh [4096,1000] -> Wht [1024][4096] bf16, rows 1000..1023 zero
  transpose_cast<<<dim3(16, 64), dim3(256), 0, stream>>>(Wh, Wht, 4096, 1000, 1024);
  // GEMM1: phi = sigmoid(feats @ Wb + bb)  (M=N=4096, K=16384), MX-fp8
  // round-2 champion schedule, GLDS prefetch 3/3/2/0
  gemm1_mx8<<<dim3(256), dim3(512), 0, stream>>>(feats, Wbt, bb, phi, 4096, 4096, 16384);
  // GEMM2 fused: out = phi @ Wht + bh (full K, bias + n<1000 mask in epilogue)
  gemm2_full<<<dim3(8, 32), dim3(256), 0, stream>>>(phi, Wht, bh, out, 4096, 1024, 4096);
}